// Round 4
// baseline (266.638 us; speedup 1.0000x reference)
//
#include <hip/hip_runtime.h>
#include <math.h>

#define ALPHA 0.12f
#define BETA  0.88f
#define OMEGA 6.0f
#define TWO_PI 6.28318530717958647692f

constexpr int Bn   = 4;
constexpr int Tn   = 4096;
constexpr int Dn   = 2048;
constexpr int HALF = Dn / 2;      // 1024
constexpr int L    = 32;          // chunk length (smaller -> more parallelism)
constexpr int NC   = Tn / L;      // 128 chunks

typedef float fx4 __attribute__((ext_vector_type(4)));

constexpr float beta_pow(int n) {
    float r = 1.0f;
    for (int i = 0; i < n; ++i) r *= BETA;
    return r;
}
constexpr float BETA_L = beta_pow(L);   // 0.88^32

// ---------------------------------------------------------------------------
// Kernel 1: per-chunk local scan endpoint (zero init), fx4 lanes.
// S[b,c,d] = sum_{i=0..L-1} BETA^(L-1-i) * u[b, c*L+i, d]
// threads = Bn*NC*Dn/4 = 262144 -> 1024 blocks (16 waves/CU, 4/SIMD).
// ---------------------------------------------------------------------------
__global__ void k_chunksum(const float* __restrict__ x,
                           const float* __restrict__ input_scale,
                           float* __restrict__ S) {
    int gid = blockIdx.x * blockDim.x + threadIdx.x;
    int d4 = gid & (Dn / 4 - 1);          // 0..511
    int c  = (gid >> 9) & (NC - 1);       // 0..127
    int b  = gid >> 16;                   // 0..3
    const float sc = ALPHA * (*input_scale);

    const fx4* xp = (const fx4*)(x + ((size_t)b * Tn + (size_t)c * L) * Dn) + d4;
    fx4 m = (fx4)(0.0f);
#pragma unroll 16
    for (int i = 0; i < L; ++i) {
        fx4 v = xp[(size_t)i * (Dn / 4)];
        m = BETA * m + sc * v;
    }
    ((fx4*)S)[gid] = m;   // gid == (b*NC + c)*(Dn/4) + d4
}

// ---------------------------------------------------------------------------
// Kernel 2 (fused): blocks [0,32): sequential carry combine over chunks,
// scalar lanes in place (loads are independent -> pipelineable);
// blocks [32,48): theta cos/sin table.
// ---------------------------------------------------------------------------
__global__ void k_mid(float* __restrict__ SC,
                      const float* __restrict__ mem_state,
                      float* __restrict__ ctab, float* __restrict__ stab,
                      const int* __restrict__ step_idx) {
    if (blockIdx.x < 32) {
        int gid = blockIdx.x * blockDim.x + threadIdx.x;  // 0..8191
        int d = gid & (Dn - 1);
        int b = gid >> 11;
        float m = mem_state[d];
        float* base = SC + (size_t)b * NC * Dn + d;
#pragma unroll 8
        for (int c = 0; c < NC; ++c) {
            float s = base[(size_t)c * Dn];
            base[(size_t)c * Dn] = m;                     // carry-in for chunk c
            m = BETA_L * m + s;
        }
    } else {
        int t = (blockIdx.x - 32) * blockDim.x + threadIdx.x;  // 0..4095
        float tg = (float)(t + 1 + *step_idx);
        float theta = fmodf(OMEGA * log1pf(tg), TWO_PI);
        ctab[t] = cosf(theta);
        stab[t] = sinf(theta);
    }
}

// ---------------------------------------------------------------------------
// Kernel 3: final pass, fx4 lanes over pair index p.
// threads = Bn*NC*HALF/4 = 131072 -> 512 blocks (8 waves/CU, 2/SIMD).
// x re-read should hit L3 (resident from k_chunksum); nt stores keep it there.
// ---------------------------------------------------------------------------
__global__ void k_final(const float* __restrict__ x,
                        const float* __restrict__ gate,
                        const float* __restrict__ input_scale,
                        const float* __restrict__ ctab,
                        const float* __restrict__ stab,
                        const float* __restrict__ C,
                        float* __restrict__ out) {
    int gid = blockIdx.x * blockDim.x + threadIdx.x;
    int p4 = gid & (HALF / 4 - 1);        // 0..255
    int c  = (gid >> 8) & (NC - 1);       // 0..127 (block-uniform)
    int b  = gid >> 15;                   // 0..3

    const float sc  = ALPHA * (*input_scale);
    const float sig = 1.0f / (1.0f + expf(-(*gate)));

    size_t base = ((size_t)b * Tn + (size_t)c * L) * Dn;
    const fx4* xa = (const fx4*)(x + base) + p4;
    const fx4* xb = (const fx4*)(x + base + HALF) + p4;
    fx4* oa = (fx4*)(out + base) + p4;
    fx4* ob = (fx4*)(out + base + HALF) + p4;

    int cidx = (b * NC + c) * (Dn / 4);
    fx4 ma = ((const fx4*)C)[cidx + p4];
    fx4 mb = ((const fx4*)C)[cidx + (HALF / 4) + p4];

    int t0 = c * L;
#pragma unroll 8
    for (int i = 0; i < L; ++i) {
        fx4 va = xa[(size_t)i * (Dn / 4)];
        fx4 vb = xb[(size_t)i * (Dn / 4)];
        ma = BETA * ma + sc * va;
        mb = BETA * mb + sc * vb;
        float cth = ctab[t0 + i];
        float sth = stab[t0 + i];
        fx4 ra = va + sig * (ma * cth - mb * sth);
        fx4 rb = vb + sig * (ma * sth + mb * cth);
        __builtin_nontemporal_store(ra, &oa[(size_t)i * (Dn / 4)]);
        __builtin_nontemporal_store(rb, &ob[(size_t)i * (Dn / 4)]);
    }
}

// ---------------------------------------------------------------------------
extern "C" void kernel_launch(void* const* d_in, const int* in_sizes, int n_in,
                              void* d_out, int out_size, void* d_ws, size_t ws_size,
                              hipStream_t stream) {
    const float* x           = (const float*)d_in[0];
    const float* gate        = (const float*)d_in[1];
    const float* input_scale = (const float*)d_in[2];
    const float* mem_state   = (const float*)d_in[3];
    const int*   step_idx    = (const int*)d_in[4];
    float* out = (float*)d_out;

    float* ws   = (float*)d_ws;
    float* ctab = ws;             // Tn floats
    float* stab = ws + Tn;        // Tn floats
    float* SC   = ws + 2 * Tn;    // Bn*NC*Dn floats (4 MiB)

    k_chunksum<<<(Bn * NC * Dn / 4) / 256, 256, 0, stream>>>(x, input_scale, SC);
    k_mid<<<32 + Tn / 256, 256, 0, stream>>>(SC, mem_state, ctab, stab, step_idx);
    k_final<<<(Bn * NC * HALF / 4) / 256, 256, 0, stream>>>(x, gate, input_scale,
                                                            ctab, stab, SC, out);
}